// Round 6
// baseline (273564.478 us; speedup 1.0000x reference)
//
#include <hip/hip_runtime.h>
#include <cstdint>
#include <cstddef>

#define SEQ       32768
#define NT        512
#define START_TAG 510
#define END_TAG   511
#define NEGF      -10000.0f
#define KCH       64
#define NCH       (SEQ / KCH)   /* 512 chunks */

#define NBLK      512           /* launched; >=64 share one XCD by pigeonhole */
#define TPB       256           /* 4 waves per block (R2-proven shape) */
#define PFIX      64            /* participants (max-count XCD >= 512/8 = 64) */
#define CPB       8             /* columns per participant block */

/* HW_REG_XCC_ID (id=20), offset 0, width 32 -> simm16 = 20 | (31<<11) */
#define XCC_GETREG_IMM 63508

/* workspace layout (64B aligned)
   bp  : 32 MiB  backpointers (u16)
   M   : 512 KiB chunk-composed maps
   bd  : 2 KiB   chunk boundary tags
   AgP : 8 KiB   packed (tag<<32 | alpha_bits) ping-pong slots
   ros : roster[8] + arrival counter                                      */
#define BP_BYTES  ((size_t)SEQ * NT * sizeof(unsigned short))
#define M_OFF     (BP_BYTES)
#define M_BYTES   ((size_t)NCH * NT * sizeof(unsigned short))
#define BD_OFF    (M_OFF + M_BYTES)
#define BD_BYTES  ((size_t)NCH * sizeof(int))
#define AG_OFF    ((BD_OFF + BD_BYTES + 63) & ~(size_t)63)
#define AG_BYTES  ((size_t)2 * NT * sizeof(unsigned long long))
#define RS_OFF    (AG_OFF + AG_BYTES)

/* ---------- kernel 0: init packed alpha slots + roster ----------
   buffer0 = (tag 0, alpha_0); buffer1 = (tag ~0, junk) -> never matches.
   Re-zeroes the roster every launch (workspace is reused across iters). */
__global__ __launch_bounds__(NT) void init_k(unsigned long long* AgP, int* ros) {
    const int t = threadIdx.x;
    const float a0 = (t == START_TAG) ? 0.0f : NEGF;
    AgP[t]      = (unsigned long long)__float_as_uint(a0);
    AgP[NT + t] = ((unsigned long long)0xFFFFFFFFu << 32)
                | (unsigned long long)__float_as_uint(NEGF);
    if (t < 9) ros[t] = 0;
}

/* ---------- kernel 1: XCD-affine relay-polled Viterbi forward ----------
   512 blocks rendezvous once (roster keyed by HW_REG_XCC_ID); the XCD with
   the most blocks (>=64 by pigeonhole) is elected; its first 64 arrivals
   participate with R2's exact geometry: block rank owns columns
   [8r, 8r+8), wave wv covers {8r+2wv, +1}, lane = gp*32+m scans
   i in [16m,16m+16) with 16 transition values in registers.
   Alpha exchange: tagged 8B slots; publish = relaxed AGENT store (writes
   through the local L2 to MALL); poll = sc0 loads (local L2 hit) with an
   AGENT-scope fallback pass every 32 misses -> deadlock-free under ANY
   placement or XCC_ID misread; worst case degrades to R2 performance.
   Tag==t IS validity (value data-depends on the polled word, no fences);
   parity ping-pong + monotone tags give >=2-step overwrite lag: tag t+2
   cannot even be WRITTEN before every block consumed t, and cache
   staleness only delays visibility, never reorders it.                   */
__global__ __launch_bounds__(TPB) void viterbi_fwd(const float* __restrict__ u,
                                                   const float* __restrict__ trans,
                                                   unsigned short* __restrict__ bp,
                                                   unsigned long long* AgP,
                                                   int* ros) {
    __shared__ float4 abuf[2][NT / 4];       /* parity ping-pong, 2 KiB each */
    __shared__ int sh_rank;

    if (threadIdx.x == 0) {
        const unsigned xcc = __builtin_amdgcn_s_getreg(XCC_GETREG_IMM) & 7u;
        const int rank = __hip_atomic_fetch_add(&ros[xcc], 1, __ATOMIC_RELAXED,
                                                __HIP_MEMORY_SCOPE_AGENT);
        __hip_atomic_fetch_add(&ros[8], 1, __ATOMIC_RELEASE,
                               __HIP_MEMORY_SCOPE_AGENT);
        while (__hip_atomic_load(&ros[8], __ATOMIC_ACQUIRE,
                                 __HIP_MEMORY_SCOPE_AGENT) < NBLK) {}
        int best = 0, bc = 0;
        #pragma unroll
        for (int x = 0; x < 8; ++x) {        /* counts final after rendezvous */
            const int c = __hip_atomic_load(&ros[x], __ATOMIC_RELAXED,
                                            __HIP_MEMORY_SCOPE_AGENT);
            if (c > bc) { bc = c; best = x; }   /* strict >: lowest xcc wins */
        }
        sh_rank = ((int)xcc == best && rank < PFIX) ? rank : -1;
    }
    __syncthreads();
    const int rank = sh_rank;
    if (rank < 0) return;                    /* non-participant block exits */

    const int tid  = threadIdx.x;
    const int wv   = tid >> 6;               /* wave in block, 0..3 */
    const int lane = tid & 63;
    const int gp   = lane >> 5;              /* column within wave 0..1 */
    const int m    = lane & 31;              /* i-chunk lane 0..31 */
    const int jb   = rank * CPB + wv * 2;    /* wave's column pair base */
    const int j    = jb + gp;                /* owned output column */
    const int i0   = 16 * m;                 /* this lane's candidate base */

    /* stage this lane's 16 transition values: trans[j][i0..i0+16) */
    const float4 t0 = *(const float4*)&trans[(size_t)j * NT + i0];
    const float4 t1 = *(const float4*)&trans[(size_t)j * NT + i0 + 4];
    const float4 t2 = *(const float4*)&trans[(size_t)j * NT + i0 + 8];
    const float4 t3 = *(const float4*)&trans[(size_t)j * NT + i0 + 12];

    float uval = 0.0f;
    if (m == 0) uval = u[j];

    for (int t = 0; t < SEQ; ++t) {
        const int par = t & 1;

        /* prefetch next step's u before the barrier (overlaps wait) */
        float unext = 0.0f;
        const int tn = (t + 1 < SEQ) ? (t + 1) : t;
        if (m == 0) unext = u[(size_t)tn * NT + j];

        if (wv == 0) {
            /* poller: 8 interleaved tagged slots/lane. Fast path = sc0
               (L1-bypass, local-L2 hit). Every 32nd miss = agent-scope
               pass (reads the MALL) -> guaranteed progress.              */
            const unsigned long long* sb = AgP + (size_t)par * NT + lane;
            unsigned long long v0, v1, v2, v3, v4, v5, v6, v7;
            const unsigned expt = (unsigned)t;
            int it = 0;
            bool ok;
            do {
                if ((it++ & 31) != 31) {
                    asm volatile(
                        "global_load_dwordx2 %0, %8, off sc0\n\t"
                        "global_load_dwordx2 %1, %8, off offset:512 sc0\n\t"
                        "global_load_dwordx2 %2, %8, off offset:1024 sc0\n\t"
                        "global_load_dwordx2 %3, %8, off offset:1536 sc0\n\t"
                        "global_load_dwordx2 %4, %8, off offset:2048 sc0\n\t"
                        "global_load_dwordx2 %5, %8, off offset:2560 sc0\n\t"
                        "global_load_dwordx2 %6, %8, off offset:3072 sc0\n\t"
                        "global_load_dwordx2 %7, %8, off offset:3584 sc0\n\t"
                        "s_waitcnt vmcnt(0)"
                        : "=&v"(v0), "=&v"(v1), "=&v"(v2), "=&v"(v3),
                          "=&v"(v4), "=&v"(v5), "=&v"(v6), "=&v"(v7)
                        : "v"(sb) : "memory");
                } else {
                    v0 = __hip_atomic_load(&sb[0],   __ATOMIC_RELAXED, __HIP_MEMORY_SCOPE_AGENT);
                    v1 = __hip_atomic_load(&sb[64],  __ATOMIC_RELAXED, __HIP_MEMORY_SCOPE_AGENT);
                    v2 = __hip_atomic_load(&sb[128], __ATOMIC_RELAXED, __HIP_MEMORY_SCOPE_AGENT);
                    v3 = __hip_atomic_load(&sb[192], __ATOMIC_RELAXED, __HIP_MEMORY_SCOPE_AGENT);
                    v4 = __hip_atomic_load(&sb[256], __ATOMIC_RELAXED, __HIP_MEMORY_SCOPE_AGENT);
                    v5 = __hip_atomic_load(&sb[320], __ATOMIC_RELAXED, __HIP_MEMORY_SCOPE_AGENT);
                    v6 = __hip_atomic_load(&sb[384], __ATOMIC_RELAXED, __HIP_MEMORY_SCOPE_AGENT);
                    v7 = __hip_atomic_load(&sb[448], __ATOMIC_RELAXED, __HIP_MEMORY_SCOPE_AGENT);
                }
                ok = ((unsigned)(v0 >> 32) == expt)
                   & ((unsigned)(v1 >> 32) == expt)
                   & ((unsigned)(v2 >> 32) == expt)
                   & ((unsigned)(v3 >> 32) == expt)
                   & ((unsigned)(v4 >> 32) == expt)
                   & ((unsigned)(v5 >> 32) == expt)
                   & ((unsigned)(v6 >> 32) == expt)
                   & ((unsigned)(v7 >> 32) == expt);
            } while (!ok);

            /* scatter to LDS, XOR-swizzled: phys(i) = i ^ (((i>>5)&7)<<2) */
            float* awf = (float*)&abuf[par][0];
            { const int i_ = lane;       awf[i_ ^ (((i_ >> 5) & 7) << 2)] = __uint_as_float((unsigned)v0); }
            { const int i_ = 64 + lane;  awf[i_ ^ (((i_ >> 5) & 7) << 2)] = __uint_as_float((unsigned)v1); }
            { const int i_ = 128 + lane; awf[i_ ^ (((i_ >> 5) & 7) << 2)] = __uint_as_float((unsigned)v2); }
            { const int i_ = 192 + lane; awf[i_ ^ (((i_ >> 5) & 7) << 2)] = __uint_as_float((unsigned)v3); }
            { const int i_ = 256 + lane; awf[i_ ^ (((i_ >> 5) & 7) << 2)] = __uint_as_float((unsigned)v4); }
            { const int i_ = 320 + lane; awf[i_ ^ (((i_ >> 5) & 7) << 2)] = __uint_as_float((unsigned)v5); }
            { const int i_ = 384 + lane; awf[i_ ^ (((i_ >> 5) & 7) << 2)] = __uint_as_float((unsigned)v6); }
            { const int i_ = 448 + lane; awf[i_ ^ (((i_ >> 5) & 7) << 2)] = __uint_as_float((unsigned)v7); }
        }
        __syncthreads();                     /* alpha_t visible block-wide */

        /* 4 independent 4-candidate chains (dep depth 4), merged; ascending
           i + strict '>' / keep-left => lowest index wins ties (R2 body)  */
        float v0, v1, v2, v3; int x0, x1, x2, x3; float s;
        {   const int ib = i0;      const int pb = ib ^ (((ib >> 5) & 7) << 2);
            const float4 a = abuf[par][pb >> 2];
            v0 = a.x + t0.x; x0 = ib;
            s = a.y + t0.y; if (s > v0) { v0 = s; x0 = ib + 1; }
            s = a.z + t0.z; if (s > v0) { v0 = s; x0 = ib + 2; }
            s = a.w + t0.w; if (s > v0) { v0 = s; x0 = ib + 3; } }
        {   const int ib = i0 + 4;  const int pb = ib ^ (((ib >> 5) & 7) << 2);
            const float4 a = abuf[par][pb >> 2];
            v1 = a.x + t1.x; x1 = ib;
            s = a.y + t1.y; if (s > v1) { v1 = s; x1 = ib + 1; }
            s = a.z + t1.z; if (s > v1) { v1 = s; x1 = ib + 2; }
            s = a.w + t1.w; if (s > v1) { v1 = s; x1 = ib + 3; } }
        {   const int ib = i0 + 8;  const int pb = ib ^ (((ib >> 5) & 7) << 2);
            const float4 a = abuf[par][pb >> 2];
            v2 = a.x + t2.x; x2 = ib;
            s = a.y + t2.y; if (s > v2) { v2 = s; x2 = ib + 1; }
            s = a.z + t2.z; if (s > v2) { v2 = s; x2 = ib + 2; }
            s = a.w + t2.w; if (s > v2) { v2 = s; x2 = ib + 3; } }
        {   const int ib = i0 + 12; const int pb = ib ^ (((ib >> 5) & 7) << 2);
            const float4 a = abuf[par][pb >> 2];
            v3 = a.x + t3.x; x3 = ib;
            s = a.y + t3.y; if (s > v3) { v3 = s; x3 = ib + 1; }
            s = a.z + t3.z; if (s > v3) { v3 = s; x3 = ib + 2; }
            s = a.w + t3.w; if (s > v3) { v3 = s; x3 = ib + 3; } }
        if (v1 > v0) { v0 = v1; x0 = x1; }   /* keep-left on ties */
        if (v3 > v2) { v2 = v3; x2 = x3; }
        if (v2 > v0) { v0 = v2; x0 = x2; }
        float bv = v0; int bi = x0;

        /* 32-lane butterfly argmax (tie: lowest i wins) */
        #pragma unroll
        for (int h = 1; h <= 16; h <<= 1) {
            const float ov = __shfl_xor(bv, h);
            const int   oi = __shfl_xor(bi, h);
            if (ov > bv || (ov == bv && oi < bi)) { bv = ov; bi = oi; }
        }

        /* publish FIRST: agent store writes through local L2 toward MALL */
        if (m == 0) {
            const float na = bv + uval;
            const unsigned long long pk =
                ((unsigned long long)(unsigned)(t + 1) << 32)
                | (unsigned long long)__float_as_uint(na);
            __hip_atomic_store(&AgP[(size_t)((t + 1) & 1) * NT + j], pk,
                               __ATOMIC_RELAXED, __HIP_MEMORY_SCOPE_AGENT);
        }

        /* backpointers: lane 0 packs the wave's two columns into one dword */
        const int oi1 = __shfl(bi, 32);      /* gp=1 result */
        if (lane == 0) {
            *(unsigned*)&bp[(size_t)t * NT + jb] =
                (unsigned)(bi & 0xFFFF) | ((unsigned)oi1 << 16);
        }
        uval = unext;
    }
}

/* ---------- kernel 2: parallel chunk-map composition from bp ---------- */
__global__ __launch_bounds__(NT) void mbuild_k(const unsigned short* __restrict__ bp,
                                               unsigned short* __restrict__ M) {
    __shared__ unsigned short R[2][NT];
    const int c = (int)blockIdx.x, j = threadIdx.x;
    const size_t base = (size_t)c * KCH * NT;
    R[0][j] = bp[base + j];
    int cb = 0;
    for (int t = 1; t < KCH; ++t) {
        const unsigned short r = bp[base + (size_t)t * NT + j];
        __syncthreads();
        R[cb ^ 1][j] = R[cb][r];
        cb ^= 1;
    }
    __syncthreads();
    M[(size_t)c * NT + j] = R[cb][j];
}

/* ---------- kernel 3: terminal argmax + chunk-boundary chase ---------- */
__global__ __launch_bounds__(NT) void chase_k(const unsigned long long* __restrict__ AgP,
                                              const float* __restrict__ tr,
                                              const unsigned short* __restrict__ M,
                                              int* __restrict__ boundary,
                                              float* __restrict__ out) {
    __shared__ float sv[NT];
    __shared__ int   si[NT];
    const int j = threadIdx.x;
    /* alpha_SEQ lives in buffer 0 (SEQ even); low 32 bits = float value */
    sv[j] = __uint_as_float((unsigned)AgP[j]) + tr[(size_t)END_TAG * NT + j];
    si[j] = j;
    __syncthreads();
    for (int off = NT / 2; off > 0; off >>= 1) {
        if (j < off) {
            const float a = sv[j], b = sv[j + off];
            if (b > a || (b == a && si[j + off] < si[j])) { sv[j] = b; si[j] = si[j + off]; }
        }
        __syncthreads();
    }
    if (j == 0) {
        out[SEQ] = sv[0];                 /* path_score */
        int tag = si[0];                  /* path[32767] */
        boundary[NCH - 1] = tag;
        for (int c = NCH - 1; c >= 1; --c) {
            tag = (int)M[(size_t)c * NT + tag];
            boundary[c - 1] = tag;
        }
    }
}

/* ---------- kernel 4: 512 independent per-chunk local tracebacks ---------- */
__global__ __launch_bounds__(64) void traceback_k(const unsigned short* __restrict__ bp,
                                                  const int* __restrict__ boundary,
                                                  float* __restrict__ out) {
    if (threadIdx.x != 0) return;
    const int c    = (int)blockIdx.x;
    int       tag  = boundary[c];            /* = path[(c+1)K - 1] */
    const int tend = (c + 1) * KCH - 1;
    out[tend] = (float)tag;
    for (int t = tend - 1; t >= c * KCH; --t) {
        tag = (int)bp[(size_t)(t + 1) * NT + tag];
        out[t] = (float)tag;
    }
}

extern "C" void kernel_launch(void* const* d_in, const int* in_sizes, int n_in,
                              void* d_out, int out_size, void* d_ws, size_t ws_size,
                              hipStream_t stream) {
    const float* unary = (const float*)d_in[0];   /* (32768,1,512) f32 */
    const float* trans = (const float*)d_in[1];   /* (1,512,512)   f32 */
    float* out = (float*)d_out;                   /* [0..32767]=path, [32768]=score */
    char*  ws  = (char*)d_ws;

    unsigned short*     bp       = (unsigned short*)ws;
    unsigned short*     M        = (unsigned short*)(ws + M_OFF);
    int*                boundary = (int*)(ws + BD_OFF);
    unsigned long long* AgP      = (unsigned long long*)(ws + AG_OFF);
    int*                ros      = (int*)(ws + RS_OFF);
    (void)in_sizes; (void)n_in; (void)out_size; (void)ws_size;

    init_k<<<1, NT, 0, stream>>>(AgP, ros);
    viterbi_fwd<<<NBLK, TPB, 0, stream>>>(unary, trans, bp, AgP, ros);
    mbuild_k<<<NCH, NT, 0, stream>>>(bp, M);
    chase_k<<<1, NT, 0, stream>>>(AgP, trans, M, boundary, out);
    traceback_k<<<NCH, 64, 0, stream>>>(bp, boundary, out);
}

// Round 7
// 107678.357 us; speedup vs baseline: 2.5406x; 2.5406x over previous
//
#include <hip/hip_runtime.h>
#include <cstdint>
#include <cstddef>

#define SEQ       32768
#define NT        512
#define START_TAG 510
#define END_TAG   511
#define NEGF      -10000.0f
#define KCH       64
#define NCH       (SEQ / KCH)   /* 512 chunks */

#define NBLK      512           /* launched; >=64 share one XCD by pigeonhole */
#define TPB       256           /* 4 waves per block (R2-proven shape) */
#define PFIX      64            /* participants (max-count XCD >= 512/8 = 64) */
#define CPB       8             /* columns per participant block */

/* HW_REG_XCC_ID (id=20), offset 0, width 32 -> simm16 = 20 | (31<<11) */
#define XCC_GETREG_IMM 63508

/* workspace layout (64B aligned)
   bp  : 32 MiB  backpointers (u16)
   M   : 512 KiB chunk-composed maps
   bd  : 2 KiB   chunk boundary tags
   AgP : 8 KiB   packed (tag<<32 | alpha_bits) ping-pong slots (PLAIN stores,
                 read by sc0 polls -> lives in the elected XCD's L2)
   AgM : 8 KiB   agent-scope MIRROR of AgP (MALL) for the fallback path
   ros : roster[8] + arrival counter                                      */
#define BP_BYTES  ((size_t)SEQ * NT * sizeof(unsigned short))
#define M_OFF     (BP_BYTES)
#define M_BYTES   ((size_t)NCH * NT * sizeof(unsigned short))
#define BD_OFF    (M_OFF + M_BYTES)
#define BD_BYTES  ((size_t)NCH * sizeof(int))
#define AG_OFF    ((BD_OFF + BD_BYTES + 63) & ~(size_t)63)
#define AG_BYTES  ((size_t)2 * NT * sizeof(unsigned long long))
#define AM_OFF    (AG_OFF + AG_BYTES)
#define RS_OFF    (AM_OFF + AG_BYTES)

/* ---------- kernel 0: init packed alpha slots + mirror + roster ----------
   buffer0 = (tag 0, alpha_0); buffer1 = (tag ~0, junk) -> never matches.  */
__global__ __launch_bounds__(NT) void init_k(unsigned long long* AgP,
                                             unsigned long long* AgM, int* ros) {
    const int t = threadIdx.x;
    const float a0 = (t == START_TAG) ? 0.0f : NEGF;
    const unsigned long long v0 = (unsigned long long)__float_as_uint(a0);
    const unsigned long long v1 = ((unsigned long long)0xFFFFFFFFu << 32)
                                | (unsigned long long)__float_as_uint(NEGF);
    AgP[t] = v0;  AgP[NT + t] = v1;
    AgM[t] = v0;  AgM[NT + t] = v1;
    if (t < 9) ros[t] = 0;
}

/* ---------- kernel 1: XCD-affine relay-polled Viterbi forward ----------
   512 blocks rendezvous once (roster keyed by HW_REG_XCC_ID); the XCD with
   the most blocks (>=64 by pigeonhole) is elected; its first 64 arrivals
   participate with R2's geometry: block rank owns columns [8r, 8r+8),
   wave wv covers {8r+2wv,+1}, lane = gp*32+m scans i in [16m,16m+16).
   Alpha exchange (the R6 diagnosis fix): publish = PLAIN store into AgP
   (write-through L1 -> lands in the shared XCD L2, the intra-XCD coherence
   point) + agent-scope store into the AgM mirror (MALL, safety). Poll =
   sc0 loads on AgP (local L2 hit); every 8th miss falls back to one
   agent-scope pass on AgM -> deadlock-free under ANY placement/XCC misread.
   Tag==t IS validity; parity ping-pong + monotone tags give >=2-step
   overwrite lag (t+2 cannot be written before every block consumed t).    */
__global__ __launch_bounds__(TPB) void viterbi_fwd(const float* __restrict__ u,
                                                   const float* __restrict__ trans,
                                                   unsigned short* __restrict__ bp,
                                                   unsigned long long* AgP,
                                                   unsigned long long* AgM,
                                                   int* ros) {
    __shared__ float4 abuf[2][NT / 4];       /* parity ping-pong, 2 KiB each */
    __shared__ int sh_rank;

    if (threadIdx.x == 0) {
        const unsigned xcc = __builtin_amdgcn_s_getreg(XCC_GETREG_IMM) & 7u;
        const int rank = __hip_atomic_fetch_add(&ros[xcc], 1, __ATOMIC_RELAXED,
                                                __HIP_MEMORY_SCOPE_AGENT);
        __hip_atomic_fetch_add(&ros[8], 1, __ATOMIC_RELEASE,
                               __HIP_MEMORY_SCOPE_AGENT);
        while (__hip_atomic_load(&ros[8], __ATOMIC_ACQUIRE,
                                 __HIP_MEMORY_SCOPE_AGENT) < NBLK) {}
        int best = 0, bc = 0;
        #pragma unroll
        for (int x = 0; x < 8; ++x) {        /* counts final after rendezvous */
            const int c = __hip_atomic_load(&ros[x], __ATOMIC_RELAXED,
                                            __HIP_MEMORY_SCOPE_AGENT);
            if (c > bc) { bc = c; best = x; }   /* strict >: lowest xcc wins */
        }
        sh_rank = ((int)xcc == best && rank < PFIX) ? rank : -1;
    }
    __syncthreads();
    const int rank = sh_rank;
    if (rank < 0) return;                    /* non-participant block exits */

    const int tid  = threadIdx.x;
    const int wv   = tid >> 6;               /* wave in block, 0..3 */
    const int lane = tid & 63;
    const int gp   = lane >> 5;              /* column within wave 0..1 */
    const int m    = lane & 31;              /* i-chunk lane 0..31 */
    const int jb   = rank * CPB + wv * 2;    /* wave's column pair base */
    const int j    = jb + gp;                /* owned output column */
    const int i0   = 16 * m;                 /* this lane's candidate base */

    /* stage this lane's 16 transition values: trans[j][i0..i0+16) */
    const float4 t0 = *(const float4*)&trans[(size_t)j * NT + i0];
    const float4 t1 = *(const float4*)&trans[(size_t)j * NT + i0 + 4];
    const float4 t2 = *(const float4*)&trans[(size_t)j * NT + i0 + 8];
    const float4 t3 = *(const float4*)&trans[(size_t)j * NT + i0 + 12];

    float uval = 0.0f;
    if (m == 0) uval = u[j];

    for (int t = 0; t < SEQ; ++t) {
        const int par = t & 1;

        /* prefetch next step's u before the barrier (overlaps wait) */
        float unext = 0.0f;
        const int tn = (t + 1 < SEQ) ? (t + 1) : t;
        if (m == 0) unext = u[(size_t)tn * NT + j];

        if (wv == 0) {
            /* poller: 8 interleaved tagged slots/lane. Fast path = sc0 on
               AgP (L1-bypass, local-L2 hit; sees participants' plain
               stores). Every 8th miss = agent-scope pass on the AgM
               mirror (MALL) -> guaranteed progress under mis-election.   */
            const unsigned long long* sb = AgP + (size_t)par * NT + lane;
            const unsigned long long* mb = AgM + (size_t)par * NT + lane;
            unsigned long long v0, v1, v2, v3, v4, v5, v6, v7;
            const unsigned expt = (unsigned)t;
            int it = 0;
            bool ok;
            do {
                if ((it++ & 7) != 7) {
                    asm volatile(
                        "global_load_dwordx2 %0, %8, off sc0\n\t"
                        "global_load_dwordx2 %1, %8, off offset:512 sc0\n\t"
                        "global_load_dwordx2 %2, %8, off offset:1024 sc0\n\t"
                        "global_load_dwordx2 %3, %8, off offset:1536 sc0\n\t"
                        "global_load_dwordx2 %4, %8, off offset:2048 sc0\n\t"
                        "global_load_dwordx2 %5, %8, off offset:2560 sc0\n\t"
                        "global_load_dwordx2 %6, %8, off offset:3072 sc0\n\t"
                        "global_load_dwordx2 %7, %8, off offset:3584 sc0\n\t"
                        "s_waitcnt vmcnt(0)"
                        : "=&v"(v0), "=&v"(v1), "=&v"(v2), "=&v"(v3),
                          "=&v"(v4), "=&v"(v5), "=&v"(v6), "=&v"(v7)
                        : "v"(sb) : "memory");
                } else {
                    v0 = __hip_atomic_load(&mb[0],   __ATOMIC_RELAXED, __HIP_MEMORY_SCOPE_AGENT);
                    v1 = __hip_atomic_load(&mb[64],  __ATOMIC_RELAXED, __HIP_MEMORY_SCOPE_AGENT);
                    v2 = __hip_atomic_load(&mb[128], __ATOMIC_RELAXED, __HIP_MEMORY_SCOPE_AGENT);
                    v3 = __hip_atomic_load(&mb[192], __ATOMIC_RELAXED, __HIP_MEMORY_SCOPE_AGENT);
                    v4 = __hip_atomic_load(&mb[256], __ATOMIC_RELAXED, __HIP_MEMORY_SCOPE_AGENT);
                    v5 = __hip_atomic_load(&mb[320], __ATOMIC_RELAXED, __HIP_MEMORY_SCOPE_AGENT);
                    v6 = __hip_atomic_load(&mb[384], __ATOMIC_RELAXED, __HIP_MEMORY_SCOPE_AGENT);
                    v7 = __hip_atomic_load(&mb[448], __ATOMIC_RELAXED, __HIP_MEMORY_SCOPE_AGENT);
                }
                ok = ((unsigned)(v0 >> 32) == expt)
                   & ((unsigned)(v1 >> 32) == expt)
                   & ((unsigned)(v2 >> 32) == expt)
                   & ((unsigned)(v3 >> 32) == expt)
                   & ((unsigned)(v4 >> 32) == expt)
                   & ((unsigned)(v5 >> 32) == expt)
                   & ((unsigned)(v6 >> 32) == expt)
                   & ((unsigned)(v7 >> 32) == expt);
            } while (!ok);

            /* scatter to LDS, XOR-swizzled: phys(i) = i ^ (((i>>5)&7)<<2) */
            float* awf = (float*)&abuf[par][0];
            { const int i_ = lane;       awf[i_ ^ (((i_ >> 5) & 7) << 2)] = __uint_as_float((unsigned)v0); }
            { const int i_ = 64 + lane;  awf[i_ ^ (((i_ >> 5) & 7) << 2)] = __uint_as_float((unsigned)v1); }
            { const int i_ = 128 + lane; awf[i_ ^ (((i_ >> 5) & 7) << 2)] = __uint_as_float((unsigned)v2); }
            { const int i_ = 192 + lane; awf[i_ ^ (((i_ >> 5) & 7) << 2)] = __uint_as_float((unsigned)v3); }
            { const int i_ = 256 + lane; awf[i_ ^ (((i_ >> 5) & 7) << 2)] = __uint_as_float((unsigned)v4); }
            { const int i_ = 320 + lane; awf[i_ ^ (((i_ >> 5) & 7) << 2)] = __uint_as_float((unsigned)v5); }
            { const int i_ = 384 + lane; awf[i_ ^ (((i_ >> 5) & 7) << 2)] = __uint_as_float((unsigned)v6); }
            { const int i_ = 448 + lane; awf[i_ ^ (((i_ >> 5) & 7) << 2)] = __uint_as_float((unsigned)v7); }
        }
        __syncthreads();                     /* alpha_t visible block-wide */

        /* 4 independent 4-candidate chains (dep depth 4), merged; ascending
           i + strict '>' / keep-left => lowest index wins ties (R2 body)  */
        float v0, v1, v2, v3; int x0, x1, x2, x3; float s;
        {   const int ib = i0;      const int pb = ib ^ (((ib >> 5) & 7) << 2);
            const float4 a = abuf[par][pb >> 2];
            v0 = a.x + t0.x; x0 = ib;
            s = a.y + t0.y; if (s > v0) { v0 = s; x0 = ib + 1; }
            s = a.z + t0.z; if (s > v0) { v0 = s; x0 = ib + 2; }
            s = a.w + t0.w; if (s > v0) { v0 = s; x0 = ib + 3; } }
        {   const int ib = i0 + 4;  const int pb = ib ^ (((ib >> 5) & 7) << 2);
            const float4 a = abuf[par][pb >> 2];
            v1 = a.x + t1.x; x1 = ib;
            s = a.y + t1.y; if (s > v1) { v1 = s; x1 = ib + 1; }
            s = a.z + t1.z; if (s > v1) { v1 = s; x1 = ib + 2; }
            s = a.w + t1.w; if (s > v1) { v1 = s; x1 = ib + 3; } }
        {   const int ib = i0 + 8;  const int pb = ib ^ (((ib >> 5) & 7) << 2);
            const float4 a = abuf[par][pb >> 2];
            v2 = a.x + t2.x; x2 = ib;
            s = a.y + t2.y; if (s > v2) { v2 = s; x2 = ib + 1; }
            s = a.z + t2.z; if (s > v2) { v2 = s; x2 = ib + 2; }
            s = a.w + t2.w; if (s > v2) { v2 = s; x2 = ib + 3; } }
        {   const int ib = i0 + 12; const int pb = ib ^ (((ib >> 5) & 7) << 2);
            const float4 a = abuf[par][pb >> 2];
            v3 = a.x + t3.x; x3 = ib;
            s = a.y + t3.y; if (s > v3) { v3 = s; x3 = ib + 1; }
            s = a.z + t3.z; if (s > v3) { v3 = s; x3 = ib + 2; }
            s = a.w + t3.w; if (s > v3) { v3 = s; x3 = ib + 3; } }
        if (v1 > v0) { v0 = v1; x0 = x1; }   /* keep-left on ties */
        if (v3 > v2) { v2 = v3; x2 = x3; }
        if (v2 > v0) { v0 = v2; x0 = x2; }
        float bv = v0; int bi = x0;

        /* 32-lane butterfly argmax (tie: lowest i wins) */
        #pragma unroll
        for (int h = 1; h <= 16; h <<= 1) {
            const float ov = __shfl_xor(bv, h);
            const int   oi = __shfl_xor(bi, h);
            if (ov > bv || (ov == bv && oi < bi)) { bv = ov; bi = oi; }
        }

        /* publish: (1) agent store -> AgM mirror (MALL, safety path);
                    (2) PLAIN store -> AgP (lands in shared XCD L2: the
                        fast path the sc0 polls read)                     */
        if (m == 0) {
            const float na = bv + uval;
            const unsigned long long pk =
                ((unsigned long long)(unsigned)(t + 1) << 32)
                | (unsigned long long)__float_as_uint(na);
            const size_t idx = (size_t)((t + 1) & 1) * NT + j;
            __hip_atomic_store(&AgM[idx], pk,
                               __ATOMIC_RELAXED, __HIP_MEMORY_SCOPE_AGENT);
            unsigned long long* dst = &AgP[idx];
            asm volatile("global_store_dwordx2 %0, %1, off"
                         :: "v"(dst), "v"(pk) : "memory");
        }

        /* backpointers: lane 0 packs the wave's two columns into one dword */
        const int oi1 = __shfl(bi, 32);      /* gp=1 result */
        if (lane == 0) {
            *(unsigned*)&bp[(size_t)t * NT + jb] =
                (unsigned)(bi & 0xFFFF) | ((unsigned)oi1 << 16);
        }
        uval = unext;
    }
}

/* ---------- kernel 2: parallel chunk-map composition from bp ---------- */
__global__ __launch_bounds__(NT) void mbuild_k(const unsigned short* __restrict__ bp,
                                               unsigned short* __restrict__ M) {
    __shared__ unsigned short R[2][NT];
    const int c = (int)blockIdx.x, j = threadIdx.x;
    const size_t base = (size_t)c * KCH * NT;
    R[0][j] = bp[base + j];
    int cb = 0;
    for (int t = 1; t < KCH; ++t) {
        const unsigned short r = bp[base + (size_t)t * NT + j];
        __syncthreads();
        R[cb ^ 1][j] = R[cb][r];
        cb ^= 1;
    }
    __syncthreads();
    M[(size_t)c * NT + j] = R[cb][j];
}

/* ---------- kernel 3: terminal argmax + chunk-boundary chase ----------
   Reads AgP buffer 0 (alpha_SEQ, SEQ even); the stream's dispatch-boundary
   L2 writeback makes viterbi_fwd's plain stores visible here.             */
__global__ __launch_bounds__(NT) void chase_k(const unsigned long long* __restrict__ AgP,
                                              const float* __restrict__ tr,
                                              const unsigned short* __restrict__ M,
                                              int* __restrict__ boundary,
                                              float* __restrict__ out) {
    __shared__ float sv[NT];
    __shared__ int   si[NT];
    const int j = threadIdx.x;
    sv[j] = __uint_as_float((unsigned)AgP[j]) + tr[(size_t)END_TAG * NT + j];
    si[j] = j;
    __syncthreads();
    for (int off = NT / 2; off > 0; off >>= 1) {
        if (j < off) {
            const float a = sv[j], b = sv[j + off];
            if (b > a || (b == a && si[j + off] < si[j])) { sv[j] = b; si[j] = si[j + off]; }
        }
        __syncthreads();
    }
    if (j == 0) {
        out[SEQ] = sv[0];                 /* path_score */
        int tag = si[0];                  /* path[32767] */
        boundary[NCH - 1] = tag;
        for (int c = NCH - 1; c >= 1; --c) {
            tag = (int)M[(size_t)c * NT + tag];
            boundary[c - 1] = tag;
        }
    }
}

/* ---------- kernel 4: 512 independent per-chunk local tracebacks ---------- */
__global__ __launch_bounds__(64) void traceback_k(const unsigned short* __restrict__ bp,
                                                  const int* __restrict__ boundary,
                                                  float* __restrict__ out) {
    if (threadIdx.x != 0) return;
    const int c    = (int)blockIdx.x;
    int       tag  = boundary[c];            /* = path[(c+1)K - 1] */
    const int tend = (c + 1) * KCH - 1;
    out[tend] = (float)tag;
    for (int t = tend - 1; t >= c * KCH; --t) {
        tag = (int)bp[(size_t)(t + 1) * NT + tag];
        out[t] = (float)tag;
    }
}

extern "C" void kernel_launch(void* const* d_in, const int* in_sizes, int n_in,
                              void* d_out, int out_size, void* d_ws, size_t ws_size,
                              hipStream_t stream) {
    const float* unary = (const float*)d_in[0];   /* (32768,1,512) f32 */
    const float* trans = (const float*)d_in[1];   /* (1,512,512)   f32 */
    float* out = (float*)d_out;                   /* [0..32767]=path, [32768]=score */
    char*  ws  = (char*)d_ws;

    unsigned short*     bp       = (unsigned short*)ws;
    unsigned short*     M        = (unsigned short*)(ws + M_OFF);
    int*                boundary = (int*)(ws + BD_OFF);
    unsigned long long* AgP      = (unsigned long long*)(ws + AG_OFF);
    unsigned long long* AgM      = (unsigned long long*)(ws + AM_OFF);
    int*                ros      = (int*)(ws + RS_OFF);
    (void)in_sizes; (void)n_in; (void)out_size; (void)ws_size;

    init_k<<<1, NT, 0, stream>>>(AgP, AgM, ros);
    viterbi_fwd<<<NBLK, TPB, 0, stream>>>(unary, trans, bp, AgP, AgM, ros);
    mbuild_k<<<NCH, NT, 0, stream>>>(bp, M);
    chase_k<<<1, NT, 0, stream>>>(AgP, trans, M, boundary, out);
    traceback_k<<<NCH, 64, 0, stream>>>(bp, boundary, out);
}

// Round 8
// 83268.066 us; speedup vs baseline: 3.2853x; 1.2932x over previous
//
#include <hip/hip_runtime.h>
#include <cstdint>
#include <cstddef>

#define SEQ       32768
#define NT        512
#define START_TAG 510
#define END_TAG   511
#define NEGF      -10000.0f
#define KCH       64
#define NCH       (SEQ / KCH)   /* 512 chunks */

#define NBLK      512           /* launched; >=64 share one XCD by pigeonhole */
#define TPB       256           /* 4 waves per block (R2-proven shape) */
#define PFIX      64            /* participants (max-count XCD >= 512/8 = 64) */
#define CPB       8             /* columns per participant block */

/* workspace layout (64B aligned)
   bp  : 32 MiB  backpointers (u16)
   M   : 512 KiB chunk-composed maps
   bd  : 2 KiB   chunk boundary tags
   AgP : 8 KiB   packed (tag<<32 | alpha_bits) ping-pong slots (PLAIN stores,
                 read by sc0 polls -> lives in the elected XCD's L2)
   AgM : 8 KiB   agent-scope MIRROR of AgP (MALL) for the fallback path
   ros : roster[8] + arrival counter                                      */
#define BP_BYTES  ((size_t)SEQ * NT * sizeof(unsigned short))
#define M_OFF     (BP_BYTES)
#define M_BYTES   ((size_t)NCH * NT * sizeof(unsigned short))
#define BD_OFF    (M_OFF + M_BYTES)
#define BD_BYTES  ((size_t)NCH * sizeof(int))
#define AG_OFF    ((BD_OFF + BD_BYTES + 63) & ~(size_t)63)
#define AG_BYTES  ((size_t)2 * NT * sizeof(unsigned long long))
#define AM_OFF    (AG_OFF + AG_BYTES)
#define RS_OFF    (AM_OFF + AG_BYTES)

/* ---------- kernel 0: init packed alpha slots + mirror + roster ----------
   buffer0 = (tag 0, alpha_0); buffer1 = (tag ~0, junk) -> never matches.  */
__global__ __launch_bounds__(NT) void init_k(unsigned long long* AgP,
                                             unsigned long long* AgM, int* ros) {
    const int t = threadIdx.x;
    const float a0 = (t == START_TAG) ? 0.0f : NEGF;
    const unsigned long long v0 = (unsigned long long)__float_as_uint(a0);
    const unsigned long long v1 = ((unsigned long long)0xFFFFFFFFu << 32)
                                | (unsigned long long)__float_as_uint(NEGF);
    AgP[t] = v0;  AgP[NT + t] = v1;
    AgM[t] = v0;  AgM[NT + t] = v1;
    if (t < 9) ros[t] = 0;
}

/* ---------- kernel 1: XCD-affine relay-polled Viterbi forward ----------
   512 blocks rendezvous once (roster keyed by the NAMED HW_REG_XCC_ID --
   the assembler resolves the correct hwreg id; the R6/R7 numeric encoding
   was the suspected election breaker). The XCD with the most blocks
   (>=64 by pigeonhole) is elected; its first 64 arrivals participate with
   R2's geometry: block rank owns columns [8r, 8r+8), wave wv covers
   {8r+2wv,+1}, lane = gp*32+m scans i in [16m,16m+16).
   Alpha exchange: publish = PLAIN store into AgP (write-through L1 ->
   lands dirty in the shared XCD L2) + agent-scope store into the AgM
   mirror (MALL, safety). Poll = sc0 loads on AgP (local L2); every 4th
   miss round = agent-scope pass on AgM -> deadlock-free and ~R2-speed
   under ANY placement or XCC misread.
   Tag==t IS validity; parity ping-pong + monotone tags give >=2-step
   overwrite lag (t+2 cannot be written before every block consumed t).    */
__global__ __launch_bounds__(TPB) void viterbi_fwd(const float* __restrict__ u,
                                                   const float* __restrict__ trans,
                                                   unsigned short* __restrict__ bp,
                                                   unsigned long long* AgP,
                                                   unsigned long long* AgM,
                                                   int* ros) {
    __shared__ float4 abuf[2][NT / 4];       /* parity ping-pong, 2 KiB each */
    __shared__ int sh_rank;

    if (threadIdx.x == 0) {
        unsigned xcc;
        asm volatile("s_getreg_b32 %0, hwreg(HW_REG_XCC_ID)" : "=s"(xcc));
        xcc &= 7u;
        const int rank = __hip_atomic_fetch_add(&ros[xcc], 1, __ATOMIC_RELAXED,
                                                __HIP_MEMORY_SCOPE_AGENT);
        __hip_atomic_fetch_add(&ros[8], 1, __ATOMIC_RELEASE,
                               __HIP_MEMORY_SCOPE_AGENT);
        while (__hip_atomic_load(&ros[8], __ATOMIC_ACQUIRE,
                                 __HIP_MEMORY_SCOPE_AGENT) < NBLK) {}
        int best = 0, bc = 0;
        #pragma unroll
        for (int x = 0; x < 8; ++x) {        /* counts final after rendezvous */
            const int c = __hip_atomic_load(&ros[x], __ATOMIC_RELAXED,
                                            __HIP_MEMORY_SCOPE_AGENT);
            if (c > bc) { bc = c; best = x; }   /* strict >: lowest xcc wins */
        }
        sh_rank = ((int)xcc == best && rank < PFIX) ? rank : -1;
    }
    __syncthreads();
    const int rank = sh_rank;
    if (rank < 0) return;                    /* non-participant block exits */

    const int tid  = threadIdx.x;
    const int wv   = tid >> 6;               /* wave in block, 0..3 */
    const int lane = tid & 63;
    const int gp   = lane >> 5;              /* column within wave 0..1 */
    const int m    = lane & 31;              /* i-chunk lane 0..31 */
    const int jb   = rank * CPB + wv * 2;    /* wave's column pair base */
    const int j    = jb + gp;                /* owned output column */
    const int i0   = 16 * m;                 /* this lane's candidate base */

    /* stage this lane's 16 transition values: trans[j][i0..i0+16) */
    const float4 t0 = *(const float4*)&trans[(size_t)j * NT + i0];
    const float4 t1 = *(const float4*)&trans[(size_t)j * NT + i0 + 4];
    const float4 t2 = *(const float4*)&trans[(size_t)j * NT + i0 + 8];
    const float4 t3 = *(const float4*)&trans[(size_t)j * NT + i0 + 12];

    float uval = 0.0f;
    if (m == 0) uval = u[j];

    for (int t = 0; t < SEQ; ++t) {
        const int par = t & 1;

        /* prefetch next step's u before the barrier (overlaps wait) */
        float unext = 0.0f;
        const int tn = (t + 1 < SEQ) ? (t + 1) : t;
        if (m == 0) unext = u[(size_t)tn * NT + j];

        if (wv == 0) {
            /* poller: 8 interleaved tagged slots/lane. Fast path = sc0 on
               AgP (local XCD L2; sees participants' plain stores). Every
               4th round = agent-scope pass on the AgM mirror (MALL) ->
               guaranteed progress at ~R2 speed under mis-election.       */
            const unsigned long long* sb = AgP + (size_t)par * NT + lane;
            const unsigned long long* mb = AgM + (size_t)par * NT + lane;
            unsigned long long v0, v1, v2, v3, v4, v5, v6, v7;
            const unsigned expt = (unsigned)t;
            int it = 0;
            bool ok;
            do {
                if ((it++ & 3) != 3) {
                    asm volatile(
                        "global_load_dwordx2 %0, %8, off sc0\n\t"
                        "global_load_dwordx2 %1, %8, off offset:512 sc0\n\t"
                        "global_load_dwordx2 %2, %8, off offset:1024 sc0\n\t"
                        "global_load_dwordx2 %3, %8, off offset:1536 sc0\n\t"
                        "global_load_dwordx2 %4, %8, off offset:2048 sc0\n\t"
                        "global_load_dwordx2 %5, %8, off offset:2560 sc0\n\t"
                        "global_load_dwordx2 %6, %8, off offset:3072 sc0\n\t"
                        "global_load_dwordx2 %7, %8, off offset:3584 sc0\n\t"
                        "s_waitcnt vmcnt(0)"
                        : "=&v"(v0), "=&v"(v1), "=&v"(v2), "=&v"(v3),
                          "=&v"(v4), "=&v"(v5), "=&v"(v6), "=&v"(v7)
                        : "v"(sb) : "memory");
                } else {
                    v0 = __hip_atomic_load(&mb[0],   __ATOMIC_RELAXED, __HIP_MEMORY_SCOPE_AGENT);
                    v1 = __hip_atomic_load(&mb[64],  __ATOMIC_RELAXED, __HIP_MEMORY_SCOPE_AGENT);
                    v2 = __hip_atomic_load(&mb[128], __ATOMIC_RELAXED, __HIP_MEMORY_SCOPE_AGENT);
                    v3 = __hip_atomic_load(&mb[192], __ATOMIC_RELAXED, __HIP_MEMORY_SCOPE_AGENT);
                    v4 = __hip_atomic_load(&mb[256], __ATOMIC_RELAXED, __HIP_MEMORY_SCOPE_AGENT);
                    v5 = __hip_atomic_load(&mb[320], __ATOMIC_RELAXED, __HIP_MEMORY_SCOPE_AGENT);
                    v6 = __hip_atomic_load(&mb[384], __ATOMIC_RELAXED, __HIP_MEMORY_SCOPE_AGENT);
                    v7 = __hip_atomic_load(&mb[448], __ATOMIC_RELAXED, __HIP_MEMORY_SCOPE_AGENT);
                }
                ok = ((unsigned)(v0 >> 32) == expt)
                   & ((unsigned)(v1 >> 32) == expt)
                   & ((unsigned)(v2 >> 32) == expt)
                   & ((unsigned)(v3 >> 32) == expt)
                   & ((unsigned)(v4 >> 32) == expt)
                   & ((unsigned)(v5 >> 32) == expt)
                   & ((unsigned)(v6 >> 32) == expt)
                   & ((unsigned)(v7 >> 32) == expt);
            } while (!ok);

            /* scatter to LDS, XOR-swizzled: phys(i) = i ^ (((i>>5)&7)<<2) */
            float* awf = (float*)&abuf[par][0];
            { const int i_ = lane;       awf[i_ ^ (((i_ >> 5) & 7) << 2)] = __uint_as_float((unsigned)v0); }
            { const int i_ = 64 + lane;  awf[i_ ^ (((i_ >> 5) & 7) << 2)] = __uint_as_float((unsigned)v1); }
            { const int i_ = 128 + lane; awf[i_ ^ (((i_ >> 5) & 7) << 2)] = __uint_as_float((unsigned)v2); }
            { const int i_ = 192 + lane; awf[i_ ^ (((i_ >> 5) & 7) << 2)] = __uint_as_float((unsigned)v3); }
            { const int i_ = 256 + lane; awf[i_ ^ (((i_ >> 5) & 7) << 2)] = __uint_as_float((unsigned)v4); }
            { const int i_ = 320 + lane; awf[i_ ^ (((i_ >> 5) & 7) << 2)] = __uint_as_float((unsigned)v5); }
            { const int i_ = 384 + lane; awf[i_ ^ (((i_ >> 5) & 7) << 2)] = __uint_as_float((unsigned)v6); }
            { const int i_ = 448 + lane; awf[i_ ^ (((i_ >> 5) & 7) << 2)] = __uint_as_float((unsigned)v7); }
        }
        __syncthreads();                     /* alpha_t visible block-wide */

        /* 4 independent 4-candidate chains (dep depth 4), merged; ascending
           i + strict '>' / keep-left => lowest index wins ties (R2 body)  */
        float v0, v1, v2, v3; int x0, x1, x2, x3; float s;
        {   const int ib = i0;      const int pb = ib ^ (((ib >> 5) & 7) << 2);
            const float4 a = abuf[par][pb >> 2];
            v0 = a.x + t0.x; x0 = ib;
            s = a.y + t0.y; if (s > v0) { v0 = s; x0 = ib + 1; }
            s = a.z + t0.z; if (s > v0) { v0 = s; x0 = ib + 2; }
            s = a.w + t0.w; if (s > v0) { v0 = s; x0 = ib + 3; } }
        {   const int ib = i0 + 4;  const int pb = ib ^ (((ib >> 5) & 7) << 2);
            const float4 a = abuf[par][pb >> 2];
            v1 = a.x + t1.x; x1 = ib;
            s = a.y + t1.y; if (s > v1) { v1 = s; x1 = ib + 1; }
            s = a.z + t1.z; if (s > v1) { v1 = s; x1 = ib + 2; }
            s = a.w + t1.w; if (s > v1) { v1 = s; x1 = ib + 3; } }
        {   const int ib = i0 + 8;  const int pb = ib ^ (((ib >> 5) & 7) << 2);
            const float4 a = abuf[par][pb >> 2];
            v2 = a.x + t2.x; x2 = ib;
            s = a.y + t2.y; if (s > v2) { v2 = s; x2 = ib + 1; }
            s = a.z + t2.z; if (s > v2) { v2 = s; x2 = ib + 2; }
            s = a.w + t2.w; if (s > v2) { v2 = s; x2 = ib + 3; } }
        {   const int ib = i0 + 12; const int pb = ib ^ (((ib >> 5) & 7) << 2);
            const float4 a = abuf[par][pb >> 2];
            v3 = a.x + t3.x; x3 = ib;
            s = a.y + t3.y; if (s > v3) { v3 = s; x3 = ib + 1; }
            s = a.z + t3.z; if (s > v3) { v3 = s; x3 = ib + 2; }
            s = a.w + t3.w; if (s > v3) { v3 = s; x3 = ib + 3; } }
        if (v1 > v0) { v0 = v1; x0 = x1; }   /* keep-left on ties */
        if (v3 > v2) { v2 = v3; x2 = x3; }
        if (v2 > v0) { v0 = v2; x0 = x2; }
        float bv = v0; int bi = x0;

        /* 32-lane butterfly argmax (tie: lowest i wins) */
        #pragma unroll
        for (int h = 1; h <= 16; h <<= 1) {
            const float ov = __shfl_xor(bv, h);
            const int   oi = __shfl_xor(bi, h);
            if (ov > bv || (ov == bv && oi < bi)) { bv = ov; bi = oi; }
        }

        /* publish: (1) PLAIN store -> AgP (lands in the shared XCD L2,
                        the fast path the sc0 polls read);
                    (2) agent store -> AgM mirror (MALL, safety path)     */
        if (m == 0) {
            const float na = bv + uval;
            const unsigned long long pk =
                ((unsigned long long)(unsigned)(t + 1) << 32)
                | (unsigned long long)__float_as_uint(na);
            const size_t idx = (size_t)((t + 1) & 1) * NT + j;
            unsigned long long* dst = &AgP[idx];
            asm volatile("global_store_dwordx2 %0, %1, off"
                         :: "v"(dst), "v"(pk) : "memory");
            __hip_atomic_store(&AgM[idx], pk,
                               __ATOMIC_RELAXED, __HIP_MEMORY_SCOPE_AGENT);
        }

        /* backpointers: lane 0 packs the wave's two columns into one dword */
        const int oi1 = __shfl(bi, 32);      /* gp=1 result */
        if (lane == 0) {
            *(unsigned*)&bp[(size_t)t * NT + jb] =
                (unsigned)(bi & 0xFFFF) | ((unsigned)oi1 << 16);
        }
        uval = unext;
    }
}

/* ---------- kernel 2: parallel chunk-map composition from bp ---------- */
__global__ __launch_bounds__(NT) void mbuild_k(const unsigned short* __restrict__ bp,
                                               unsigned short* __restrict__ M) {
    __shared__ unsigned short R[2][NT];
    const int c = (int)blockIdx.x, j = threadIdx.x;
    const size_t base = (size_t)c * KCH * NT;
    R[0][j] = bp[base + j];
    int cb = 0;
    for (int t = 1; t < KCH; ++t) {
        const unsigned short r = bp[base + (size_t)t * NT + j];
        __syncthreads();
        R[cb ^ 1][j] = R[cb][r];
        cb ^= 1;
    }
    __syncthreads();
    M[(size_t)c * NT + j] = R[cb][j];
}

/* ---------- kernel 3: terminal argmax + chunk-boundary chase ----------
   Reads AgP buffer 0 (alpha_SEQ, SEQ even); the dispatch-boundary L2
   writeback makes viterbi_fwd's plain stores visible here.                */
__global__ __launch_bounds__(NT) void chase_k(const unsigned long long* __restrict__ AgP,
                                              const float* __restrict__ tr,
                                              const unsigned short* __restrict__ M,
                                              int* __restrict__ boundary,
                                              float* __restrict__ out) {
    __shared__ float sv[NT];
    __shared__ int   si[NT];
    const int j = threadIdx.x;
    sv[j] = __uint_as_float((unsigned)AgP[j]) + tr[(size_t)END_TAG * NT + j];
    si[j] = j;
    __syncthreads();
    for (int off = NT / 2; off > 0; off >>= 1) {
        if (j < off) {
            const float a = sv[j], b = sv[j + off];
            if (b > a || (b == a && si[j + off] < si[j])) { sv[j] = b; si[j] = si[j + off]; }
        }
        __syncthreads();
    }
    if (j == 0) {
        out[SEQ] = sv[0];                 /* path_score */
        int tag = si[0];                  /* path[32767] */
        boundary[NCH - 1] = tag;
        for (int c = NCH - 1; c >= 1; --c) {
            tag = (int)M[(size_t)c * NT + tag];
            boundary[c - 1] = tag;
        }
    }
}

/* ---------- kernel 4: 512 independent per-chunk local tracebacks ---------- */
__global__ __launch_bounds__(64) void traceback_k(const unsigned short* __restrict__ bp,
                                                  const int* __restrict__ boundary,
                                                  float* __restrict__ out) {
    if (threadIdx.x != 0) return;
    const int c    = (int)blockIdx.x;
    int       tag  = boundary[c];            /* = path[(c+1)K - 1] */
    const int tend = (c + 1) * KCH - 1;
    out[tend] = (float)tag;
    for (int t = tend - 1; t >= c * KCH; --t) {
        tag = (int)bp[(size_t)(t + 1) * NT + tag];
        out[t] = (float)tag;
    }
}

extern "C" void kernel_launch(void* const* d_in, const int* in_sizes, int n_in,
                              void* d_out, int out_size, void* d_ws, size_t ws_size,
                              hipStream_t stream) {
    const float* unary = (const float*)d_in[0];   /* (32768,1,512) f32 */
    const float* trans = (const float*)d_in[1];   /* (1,512,512)   f32 */
    float* out = (float*)d_out;                   /* [0..32767]=path, [32768]=score */
    char*  ws  = (char*)d_ws;

    unsigned short*     bp       = (unsigned short*)ws;
    unsigned short*     M        = (unsigned short*)(ws + M_OFF);
    int*                boundary = (int*)(ws + BD_OFF);
    unsigned long long* AgP      = (unsigned long long*)(ws + AG_OFF);
    unsigned long long* AgM      = (unsigned long long*)(ws + AM_OFF);
    int*                ros      = (int*)(ws + RS_OFF);
    (void)in_sizes; (void)n_in; (void)out_size; (void)ws_size;

    init_k<<<1, NT, 0, stream>>>(AgP, AgM, ros);
    viterbi_fwd<<<NBLK, TPB, 0, stream>>>(unary, trans, bp, AgP, AgM, ros);
    mbuild_k<<<NCH, NT, 0, stream>>>(bp, M);
    chase_k<<<1, NT, 0, stream>>>(AgP, trans, M, boundary, out);
    traceback_k<<<NCH, 64, 0, stream>>>(bp, boundary, out);
}

// Round 9
// 79047.168 us; speedup vs baseline: 3.4608x; 1.0534x over previous
//
#include <hip/hip_runtime.h>
#include <cstdint>
#include <cstddef>

#define SEQ       32768
#define NT        512
#define START_TAG 510
#define END_TAG   511
#define NEGF      -10000.0f
#define KCH       64
#define NCH       (SEQ / KCH)   /* 512 chunks */

#define NBLK      64            /* forward blocks (R2-proven) */
#define TPB       384           /* 6 waves: 0-1 dedicated pollers, 2-5 compute */
#define CPB       8             /* columns owned per block */

/* workspace layout (64B aligned)
   bp  : 32 MiB  backpointers (u16)
   M   : 512 KiB chunk-composed maps
   bd  : 2 KiB   chunk boundary tags
   AgP : 8 KiB   packed (tag<<32 | alpha_bits) ping-pong slots            */
#define BP_BYTES  ((size_t)SEQ * NT * sizeof(unsigned short))
#define M_OFF     (BP_BYTES)
#define M_BYTES   ((size_t)NCH * NT * sizeof(unsigned short))
#define BD_OFF    (M_OFF + M_BYTES)
#define BD_BYTES  ((size_t)NCH * sizeof(int))
#define AG_OFF    ((BD_OFF + BD_BYTES + 63) & ~(size_t)63)

/* ---------- kernel 0: init packed alpha slots ----------
   buffer0 = (tag 0, alpha_0); buffer1 = (tag ~0, junk) -> never matches */
__global__ __launch_bounds__(NT) void init_k(unsigned long long* AgP) {
    const int t = threadIdx.x;
    const float a0 = (t == START_TAG) ? 0.0f : NEGF;
    AgP[t]      = (unsigned long long)__float_as_uint(a0);
    AgP[NT + t] = ((unsigned long long)0xFFFFFFFFu << 32)
                | (unsigned long long)__float_as_uint(NEGF);
}

/* ---------- kernel 1: overlap-polled wave-owned Viterbi forward ----------
   64 blocks x 6 waves. Waves 0-1 are DEDICATED POLLERS (256 tagged slots
   each, 4 loads/lane); waves 2-5 compute (R2's exact shape: 2 cols/wave,
   lane = gp*32+m scans i in [16m,16m+16), 16 trans values in registers).
   KEY OVERLAP: pollers pass barrier_t and immediately poll parity t+1
   while compute waves process step t -> remote publishes for t+1 are
   detected concurrently with local compute, collapsing the serial chain.
   One barrier/step is race-free: scatter(t+2) into abuf[par] occurs after
   barrier_{t+1}, which compute reaches only after reading abuf[par] at t.
   Protocol: R2's proven tagged slots, relaxed agent scope, tag==t IS
   validity (value data-depends on the polled word -> no fences); parity
   ping-pong + monotone tags give >=2-step overwrite lag.                  */
__global__ __launch_bounds__(TPB) void viterbi_fwd(const float* __restrict__ u,
                                                   const float* __restrict__ trans,
                                                   unsigned short* __restrict__ bp,
                                                   unsigned long long* AgP) {
    __shared__ float4 abuf[2][NT / 4];       /* parity ping-pong, 2 KiB each */

    const int tid  = threadIdx.x;
    const int wv   = tid >> 6;               /* 0-1 pollers, 2-5 compute */
    const int lane = tid & 63;
    const int b    = (int)blockIdx.x;

    if (wv < 2) {
        /* ---------------- dedicated poller waves ---------------- */
        const int base = wv * 256;           /* slot range [base, base+256) */
        for (int t = 0; t < SEQ; ++t) {
            const int par = t & 1;
            const unsigned long long* sb = AgP + (size_t)par * NT + base + lane;
            unsigned long long va[4];
            const unsigned expt = (unsigned)t;
            for (;;) {
                bool ok = true;
                #pragma unroll
                for (int r = 0; r < 4; ++r) {
                    va[r] = __hip_atomic_load(&sb[r * 64], __ATOMIC_RELAXED,
                                              __HIP_MEMORY_SCOPE_AGENT);
                    ok &= ((unsigned)(va[r] >> 32) == expt);
                }
                if (ok) break;
            }
            /* scatter to LDS, XOR-swizzled: phys(i) = i ^ (((i>>5)&7)<<2) */
            float* awf = (float*)&abuf[par][0];
            #pragma unroll
            for (int r = 0; r < 4; ++r) {
                const int i    = base + r * 64 + lane;
                const int phys = i ^ (((i >> 5) & 7) << 2);
                awf[phys] = __uint_as_float((unsigned)va[r]);
            }
            __syncthreads();                 /* alpha_t visible block-wide;
                                                poller loops straight to t+1 */
        }
    } else {
        /* ---------------- compute waves (R2 body) ---------------- */
        const int cw   = wv - 2;             /* 0..3 */
        const int gp   = lane >> 5;          /* column within wave 0..1 */
        const int m    = lane & 31;          /* i-chunk lane 0..31 */
        const int jb   = b * CPB + cw * 2;   /* wave's column pair base */
        const int j    = jb + gp;            /* owned output column */
        const int i0   = 16 * m;             /* this lane's candidate base */

        /* stage this lane's 16 transition values: trans[j][i0..i0+16) */
        const float4 t0 = *(const float4*)&trans[(size_t)j * NT + i0];
        const float4 t1 = *(const float4*)&trans[(size_t)j * NT + i0 + 4];
        const float4 t2 = *(const float4*)&trans[(size_t)j * NT + i0 + 8];
        const float4 t3 = *(const float4*)&trans[(size_t)j * NT + i0 + 12];

        float uval = 0.0f;
        if (m == 0) uval = u[j];

        for (int t = 0; t < SEQ; ++t) {
            const int par = t & 1;

            /* prefetch next step's u before the barrier (overlaps wait) */
            float unext = 0.0f;
            const int tn = (t + 1 < SEQ) ? (t + 1) : t;
            if (m == 0) unext = u[(size_t)tn * NT + j];

            __syncthreads();                 /* wait for pollers' scatter of t */

            /* 4 independent 4-candidate chains (dep depth 4), merged;
               ascending i + strict '>' / keep-left => lowest index on ties */
            float v0, v1, v2, v3; int x0, x1, x2, x3; float s;
            {   const int ib = i0;      const int pb = ib ^ (((ib >> 5) & 7) << 2);
                const float4 a = abuf[par][pb >> 2];
                v0 = a.x + t0.x; x0 = ib;
                s = a.y + t0.y; if (s > v0) { v0 = s; x0 = ib + 1; }
                s = a.z + t0.z; if (s > v0) { v0 = s; x0 = ib + 2; }
                s = a.w + t0.w; if (s > v0) { v0 = s; x0 = ib + 3; } }
            {   const int ib = i0 + 4;  const int pb = ib ^ (((ib >> 5) & 7) << 2);
                const float4 a = abuf[par][pb >> 2];
                v1 = a.x + t1.x; x1 = ib;
                s = a.y + t1.y; if (s > v1) { v1 = s; x1 = ib + 1; }
                s = a.z + t1.z; if (s > v1) { v1 = s; x1 = ib + 2; }
                s = a.w + t1.w; if (s > v1) { v1 = s; x1 = ib + 3; } }
            {   const int ib = i0 + 8;  const int pb = ib ^ (((ib >> 5) & 7) << 2);
                const float4 a = abuf[par][pb >> 2];
                v2 = a.x + t2.x; x2 = ib;
                s = a.y + t2.y; if (s > v2) { v2 = s; x2 = ib + 1; }
                s = a.z + t2.z; if (s > v2) { v2 = s; x2 = ib + 2; }
                s = a.w + t2.w; if (s > v2) { v2 = s; x2 = ib + 3; } }
            {   const int ib = i0 + 12; const int pb = ib ^ (((ib >> 5) & 7) << 2);
                const float4 a = abuf[par][pb >> 2];
                v3 = a.x + t3.x; x3 = ib;
                s = a.y + t3.y; if (s > v3) { v3 = s; x3 = ib + 1; }
                s = a.z + t3.z; if (s > v3) { v3 = s; x3 = ib + 2; }
                s = a.w + t3.w; if (s > v3) { v3 = s; x3 = ib + 3; } }
            if (v1 > v0) { v0 = v1; x0 = x1; }   /* keep-left on ties */
            if (v3 > v2) { v2 = v3; x2 = x3; }
            if (v2 > v0) { v0 = v2; x0 = x2; }
            float bv = v0; int bi = x0;

            /* 32-lane butterfly argmax (tie: lowest i wins) */
            #pragma unroll
            for (int h = 1; h <= 16; h <<= 1) {
                const float ov = __shfl_xor(bv, h);
                const int   oi = __shfl_xor(bi, h);
                if (ov > bv || (ov == bv && oi < bi)) { bv = ov; bi = oi; }
            }

            /* publish FIRST: start the agent-store drain immediately */
            if (m == 0) {
                const float na = bv + uval;
                const unsigned long long pk =
                    ((unsigned long long)(unsigned)(t + 1) << 32)
                    | (unsigned long long)__float_as_uint(na);
                __hip_atomic_store(&AgP[(size_t)((t + 1) & 1) * NT + j], pk,
                                   __ATOMIC_RELAXED, __HIP_MEMORY_SCOPE_AGENT);
            }

            /* backpointers: lane 0 packs the wave's two columns */
            const int oi1 = __shfl(bi, 32);  /* gp=1 result */
            if (lane == 0) {
                *(unsigned*)&bp[(size_t)t * NT + jb] =
                    (unsigned)(bi & 0xFFFF) | ((unsigned)oi1 << 16);
            }
            uval = unext;
        }
    }
}

/* ---------- kernel 2: parallel chunk-map composition from bp ---------- */
__global__ __launch_bounds__(NT) void mbuild_k(const unsigned short* __restrict__ bp,
                                               unsigned short* __restrict__ M) {
    __shared__ unsigned short R[2][NT];
    const int c = (int)blockIdx.x, j = threadIdx.x;
    const size_t base = (size_t)c * KCH * NT;
    R[0][j] = bp[base + j];
    int cb = 0;
    for (int t = 1; t < KCH; ++t) {
        const unsigned short r = bp[base + (size_t)t * NT + j];
        __syncthreads();
        R[cb ^ 1][j] = R[cb][r];
        cb ^= 1;
    }
    __syncthreads();
    M[(size_t)c * NT + j] = R[cb][j];
}

/* ---------- kernel 3: terminal argmax + chunk-boundary chase ---------- */
__global__ __launch_bounds__(NT) void chase_k(const unsigned long long* __restrict__ AgP,
                                              const float* __restrict__ tr,
                                              const unsigned short* __restrict__ M,
                                              int* __restrict__ boundary,
                                              float* __restrict__ out) {
    __shared__ float sv[NT];
    __shared__ int   si[NT];
    const int j = threadIdx.x;
    /* alpha_SEQ lives in buffer 0 (SEQ even); low 32 bits = float value */
    sv[j] = __uint_as_float((unsigned)AgP[j]) + tr[(size_t)END_TAG * NT + j];
    si[j] = j;
    __syncthreads();
    for (int off = NT / 2; off > 0; off >>= 1) {
        if (j < off) {
            const float a = sv[j], b = sv[j + off];
            if (b > a || (b == a && si[j + off] < si[j])) { sv[j] = b; si[j] = si[j + off]; }
        }
        __syncthreads();
    }
    if (j == 0) {
        out[SEQ] = sv[0];                 /* path_score */
        int tag = si[0];                  /* path[32767] */
        boundary[NCH - 1] = tag;
        for (int c = NCH - 1; c >= 1; --c) {
            tag = (int)M[(size_t)c * NT + tag];
            boundary[c - 1] = tag;
        }
    }
}

/* ---------- kernel 4: 512 independent per-chunk local tracebacks ---------- */
__global__ __launch_bounds__(64) void traceback_k(const unsigned short* __restrict__ bp,
                                                  const int* __restrict__ boundary,
                                                  float* __restrict__ out) {
    if (threadIdx.x != 0) return;
    const int c    = (int)blockIdx.x;
    int       tag  = boundary[c];            /* = path[(c+1)K - 1] */
    const int tend = (c + 1) * KCH - 1;
    out[tend] = (float)tag;
    for (int t = tend - 1; t >= c * KCH; --t) {
        tag = (int)bp[(size_t)(t + 1) * NT + tag];
        out[t] = (float)tag;
    }
}

extern "C" void kernel_launch(void* const* d_in, const int* in_sizes, int n_in,
                              void* d_out, int out_size, void* d_ws, size_t ws_size,
                              hipStream_t stream) {
    const float* unary = (const float*)d_in[0];   /* (32768,1,512) f32 */
    const float* trans = (const float*)d_in[1];   /* (1,512,512)   f32 */
    float* out = (float*)d_out;                   /* [0..32767]=path, [32768]=score */
    char*  ws  = (char*)d_ws;

    unsigned short*     bp       = (unsigned short*)ws;
    unsigned short*     M        = (unsigned short*)(ws + M_OFF);
    int*                boundary = (int*)(ws + BD_OFF);
    unsigned long long* AgP      = (unsigned long long*)(ws + AG_OFF);
    (void)in_sizes; (void)n_in; (void)out_size; (void)ws_size;

    init_k<<<1, NT, 0, stream>>>(AgP);
    viterbi_fwd<<<NBLK, TPB, 0, stream>>>(unary, trans, bp, AgP);
    mbuild_k<<<NCH, NT, 0, stream>>>(bp, M);
    chase_k<<<1, NT, 0, stream>>>(AgP, trans, M, boundary, out);
    traceback_k<<<NCH, 64, 0, stream>>>(bp, boundary, out);
}

// Round 10
// 63406.152 us; speedup vs baseline: 4.3145x; 1.2467x over previous
//
#include <hip/hip_runtime.h>
#include <cstdint>
#include <cstddef>

#define SEQ       32768
#define NT        512
#define START_TAG 510
#define END_TAG   511
#define NEGF      -10000.0f
#define KCH       64
#define NCH       (SEQ / KCH)   /* 512 chunks */

#define NBLK      64            /* forward blocks (R2-proven geometry) */
#define TPB       256           /* 4 waves per block */
#define CPB       8             /* columns owned per block */

/* workspace layout (64B aligned)
   bp  : 32 MiB  backpointers (u16)
   M   : 512 KiB chunk-composed maps
   bd  : 2 KiB   chunk boundary tags
   AgP : 8 KiB   packed (tag<<32 | alpha_bits) ping-pong slots            */
#define BP_BYTES  ((size_t)SEQ * NT * sizeof(unsigned short))
#define M_OFF     (BP_BYTES)
#define M_BYTES   ((size_t)NCH * NT * sizeof(unsigned short))
#define BD_OFF    (M_OFF + M_BYTES)
#define BD_BYTES  ((size_t)NCH * sizeof(int))
#define AG_OFF    ((BD_OFF + BD_BYTES + 63) & ~(size_t)63)

/* ---------- kernel 0: init packed alpha slots ----------
   buffer0 = (tag 0, alpha_0); buffer1 = (tag ~0, junk) -> never matches */
__global__ __launch_bounds__(NT) void init_k(unsigned long long* AgP) {
    const int t = threadIdx.x;
    const float a0 = (t == START_TAG) ? 0.0f : NEGF;
    AgP[t]      = (unsigned long long)__float_as_uint(a0);
    AgP[NT + t] = ((unsigned long long)0xFFFFFFFFu << 32)
                | (unsigned long long)__float_as_uint(NEGF);
}

/* ---------- kernel 1: distributed-poll wave-owned Viterbi forward ----------
   R2's exact geometry (64 blocks x 4 waves, 2 cols/wave, 16 cands/lane) with
   ONE change: the 512-slot poll is SPLIT across the 4 waves -- wave wv polls
   only its 128-slot quarter (2 loads/lane instead of 8), scatters its
   quarter into the parity LDS buffer, and the single per-step __syncthreads
   releases the block. Shorter rounds (~1 RT) and 4x sampling frequency cut
   the detect-quantization term of the serial chain; each wave's first poll
   round also overlaps its own publish drain.
   Protocol unchanged (R2-proven): tagged 8B slots, relaxed agent scope,
   tag==t IS validity (value data-depends on the polled word, no fences);
   parity ping-pong + monotone tags + the transitive barrier chain give a
   provable >=2-step overwrite lag. The barrier now requires ALL quarters
   detected, which only strengthens the ordering argument.                  */
__global__ __launch_bounds__(TPB) void viterbi_fwd(const float* __restrict__ u,
                                                   const float* __restrict__ trans,
                                                   unsigned short* __restrict__ bp,
                                                   unsigned long long* AgP) {
    __shared__ float4 abuf[2][NT / 4];       /* parity ping-pong, 2 KiB each */

    const int tid  = threadIdx.x;
    const int wv   = tid >> 6;               /* wave in block, 0..3 */
    const int lane = tid & 63;
    const int gp   = lane >> 5;              /* column within wave 0..1 */
    const int m    = lane & 31;              /* i-chunk lane 0..31 */
    const int b    = (int)blockIdx.x;
    const int jb   = b * CPB + wv * 2;       /* wave's column pair base */
    const int j    = jb + gp;                /* owned output column */
    const int i0   = 16 * m;                 /* this lane's candidate base */
    const int qb   = wv << 7;                /* this wave's poll-quarter base */

    /* stage this lane's 16 transition values: trans[j][i0..i0+16) */
    const float4 t0 = *(const float4*)&trans[(size_t)j * NT + i0];
    const float4 t1 = *(const float4*)&trans[(size_t)j * NT + i0 + 4];
    const float4 t2 = *(const float4*)&trans[(size_t)j * NT + i0 + 8];
    const float4 t3 = *(const float4*)&trans[(size_t)j * NT + i0 + 12];

    /* u prefetch for t=0 (column leaders only) */
    float uval = 0.0f;
    if (m == 0) uval = u[j];

    for (int t = 0; t < SEQ; ++t) {
        const int par = t & 1;

        /* prefetch next step's u before the barrier (overlaps wait) */
        float unext = 0.0f;
        const int tn = (t + 1 < SEQ) ? (t + 1) : t;
        if (m == 0) unext = u[(size_t)tn * NT + j];

        /* distributed poll: this wave's 128-slot quarter, 2 loads/lane.
           Short rounds (~1 RT) -> fine-grained detect sampling.          */
        {
            const unsigned long long* sb = AgP + (size_t)par * NT + qb + lane;
            unsigned long long va0, va1;
            const unsigned expt = (unsigned)t;
            for (;;) {
                va0 = __hip_atomic_load(&sb[0],  __ATOMIC_RELAXED,
                                        __HIP_MEMORY_SCOPE_AGENT);
                va1 = __hip_atomic_load(&sb[64], __ATOMIC_RELAXED,
                                        __HIP_MEMORY_SCOPE_AGENT);
                if (((unsigned)(va0 >> 32) == expt) &
                    ((unsigned)(va1 >> 32) == expt)) break;
            }
            /* scatter own quarter, XOR-swizzled: phys(i)=i^(((i>>5)&7)<<2) */
            float* awf = (float*)&abuf[par][0];
            const int ia = qb + lane;
            const int ib2 = qb + 64 + lane;
            awf[ia  ^ (((ia  >> 5) & 7) << 2)] = __uint_as_float((unsigned)va0);
            awf[ib2 ^ (((ib2 >> 5) & 7) << 2)] = __uint_as_float((unsigned)va1);
        }
        __syncthreads();                     /* all quarters of alpha_t ready */

        /* 4 independent 4-candidate chains (dep depth 4), merged; ascending
           i + strict '>' / keep-left => lowest index wins ties (R2 body)  */
        float v0, v1, v2, v3; int x0, x1, x2, x3; float s;
        {   const int ib = i0;      const int pb = ib ^ (((ib >> 5) & 7) << 2);
            const float4 a = abuf[par][pb >> 2];
            v0 = a.x + t0.x; x0 = ib;
            s = a.y + t0.y; if (s > v0) { v0 = s; x0 = ib + 1; }
            s = a.z + t0.z; if (s > v0) { v0 = s; x0 = ib + 2; }
            s = a.w + t0.w; if (s > v0) { v0 = s; x0 = ib + 3; } }
        {   const int ib = i0 + 4;  const int pb = ib ^ (((ib >> 5) & 7) << 2);
            const float4 a = abuf[par][pb >> 2];
            v1 = a.x + t1.x; x1 = ib;
            s = a.y + t1.y; if (s > v1) { v1 = s; x1 = ib + 1; }
            s = a.z + t1.z; if (s > v1) { v1 = s; x1 = ib + 2; }
            s = a.w + t1.w; if (s > v1) { v1 = s; x1 = ib + 3; } }
        {   const int ib = i0 + 8;  const int pb = ib ^ (((ib >> 5) & 7) << 2);
            const float4 a = abuf[par][pb >> 2];
            v2 = a.x + t2.x; x2 = ib;
            s = a.y + t2.y; if (s > v2) { v2 = s; x2 = ib + 1; }
            s = a.z + t2.z; if (s > v2) { v2 = s; x2 = ib + 2; }
            s = a.w + t2.w; if (s > v2) { v2 = s; x2 = ib + 3; } }
        {   const int ib = i0 + 12; const int pb = ib ^ (((ib >> 5) & 7) << 2);
            const float4 a = abuf[par][pb >> 2];
            v3 = a.x + t3.x; x3 = ib;
            s = a.y + t3.y; if (s > v3) { v3 = s; x3 = ib + 1; }
            s = a.z + t3.z; if (s > v3) { v3 = s; x3 = ib + 2; }
            s = a.w + t3.w; if (s > v3) { v3 = s; x3 = ib + 3; } }
        if (v1 > v0) { v0 = v1; x0 = x1; }   /* keep-left on ties */
        if (v3 > v2) { v2 = v3; x2 = x3; }
        if (v2 > v0) { v0 = v2; x0 = x2; }
        float bv = v0; int bi = x0;

        /* 32-lane butterfly argmax (tie: lowest i wins) */
        #pragma unroll
        for (int h = 1; h <= 16; h <<= 1) {
            const float ov = __shfl_xor(bv, h);
            const int   oi = __shfl_xor(bi, h);
            if (ov > bv || (ov == bv && oi < bi)) { bv = ov; bi = oi; }
        }

        /* publish FIRST: start the agent-store drain as early as possible */
        if (m == 0) {
            const float na = bv + uval;
            const unsigned long long pk =
                ((unsigned long long)(unsigned)(t + 1) << 32)
                | (unsigned long long)__float_as_uint(na);
            __hip_atomic_store(&AgP[(size_t)((t + 1) & 1) * NT + j], pk,
                               __ATOMIC_RELAXED, __HIP_MEMORY_SCOPE_AGENT);
        }

        /* backpointers: lane 0 packs the wave's two columns into one dword */
        const int oi1 = __shfl(bi, 32);      /* gp=1 result */
        if (lane == 0) {
            *(unsigned*)&bp[(size_t)t * NT + jb] =
                (unsigned)(bi & 0xFFFF) | ((unsigned)oi1 << 16);
        }
        uval = unext;
    }
}

/* ---------- kernel 2: parallel chunk-map composition from bp ---------- */
__global__ __launch_bounds__(NT) void mbuild_k(const unsigned short* __restrict__ bp,
                                               unsigned short* __restrict__ M) {
    __shared__ unsigned short R[2][NT];
    const int c = (int)blockIdx.x, j = threadIdx.x;
    const size_t base = (size_t)c * KCH * NT;
    R[0][j] = bp[base + j];
    int cb = 0;
    for (int t = 1; t < KCH; ++t) {
        const unsigned short r = bp[base + (size_t)t * NT + j];
        __syncthreads();
        R[cb ^ 1][j] = R[cb][r];
        cb ^= 1;
    }
    __syncthreads();
    M[(size_t)c * NT + j] = R[cb][j];
}

/* ---------- kernel 3: terminal argmax + chunk-boundary chase ---------- */
__global__ __launch_bounds__(NT) void chase_k(const unsigned long long* __restrict__ AgP,
                                              const float* __restrict__ tr,
                                              const unsigned short* __restrict__ M,
                                              int* __restrict__ boundary,
                                              float* __restrict__ out) {
    __shared__ float sv[NT];
    __shared__ int   si[NT];
    const int j = threadIdx.x;
    /* alpha_SEQ lives in buffer 0 (SEQ even); low 32 bits = float value */
    sv[j] = __uint_as_float((unsigned)AgP[j]) + tr[(size_t)END_TAG * NT + j];
    si[j] = j;
    __syncthreads();
    for (int off = NT / 2; off > 0; off >>= 1) {
        if (j < off) {
            const float a = sv[j], b = sv[j + off];
            if (b > a || (b == a && si[j + off] < si[j])) { sv[j] = b; si[j] = si[j + off]; }
        }
        __syncthreads();
    }
    if (j == 0) {
        out[SEQ] = sv[0];                 /* path_score */
        int tag = si[0];                  /* path[32767] */
        boundary[NCH - 1] = tag;
        for (int c = NCH - 1; c >= 1; --c) {
            tag = (int)M[(size_t)c * NT + tag];
            boundary[c - 1] = tag;
        }
    }
}

/* ---------- kernel 4: 512 independent per-chunk local tracebacks ---------- */
__global__ __launch_bounds__(64) void traceback_k(const unsigned short* __restrict__ bp,
                                                  const int* __restrict__ boundary,
                                                  float* __restrict__ out) {
    if (threadIdx.x != 0) return;
    const int c    = (int)blockIdx.x;
    int       tag  = boundary[c];            /* = path[(c+1)K - 1] */
    const int tend = (c + 1) * KCH - 1;
    out[tend] = (float)tag;
    for (int t = tend - 1; t >= c * KCH; --t) {
        tag = (int)bp[(size_t)(t + 1) * NT + tag];
        out[t] = (float)tag;
    }
}

extern "C" void kernel_launch(void* const* d_in, const int* in_sizes, int n_in,
                              void* d_out, int out_size, void* d_ws, size_t ws_size,
                              hipStream_t stream) {
    const float* unary = (const float*)d_in[0];   /* (32768,1,512) f32 */
    const float* trans = (const float*)d_in[1];   /* (1,512,512)   f32 */
    float* out = (float*)d_out;                   /* [0..32767]=path, [32768]=score */
    char*  ws  = (char*)d_ws;

    unsigned short*     bp       = (unsigned short*)ws;
    unsigned short*     M        = (unsigned short*)(ws + M_OFF);
    int*                boundary = (int*)(ws + BD_OFF);
    unsigned long long* AgP      = (unsigned long long*)(ws + AG_OFF);
    (void)in_sizes; (void)n_in; (void)out_size; (void)ws_size;

    init_k<<<1, NT, 0, stream>>>(AgP);
    viterbi_fwd<<<NBLK, TPB, 0, stream>>>(unary, trans, bp, AgP);
    mbuild_k<<<NCH, NT, 0, stream>>>(bp, M);
    chase_k<<<1, NT, 0, stream>>>(AgP, trans, M, boundary, out);
    traceback_k<<<NCH, 64, 0, stream>>>(bp, boundary, out);
}